// Round 18
// baseline (74.978 us; speedup 1.0000x reference)
//
#include <hip/hip_runtime.h>
#include <stdint.h>

#define H_ 384
#define W_ 512
#define HW_ (H_ * W_)
#define NIMG 32
#define EPSF 1e-6f
#define HBLK 16            // hist blocks per image
#define HTHR 512           // threads per hist block
#define PXB (HW_ / HBLK)   // 12288 px per hist block
#define CITER (PXB / (HTHR * 4))  // 6
#define MBLK 192           // main blocks per image (4 px/thread, 1024 px/block)
#define NPARTS (MBLK * NIMG)
#define SENT 0xFFFFFFFFu

// ---- workspace layout (u32 indices). NOTHING pre-zeroed; every buffer is ----
// ---- fully overwritten before read each call. No fences/done counters    ----
// ---- (r9/r11). No keys (r13). Normals stay in main (r16/r17: moving them ----
// ---- elsewhere costs the same). r18: pts_pred staged via LDS, unit-stride.----
#define OFF_MSUM   0                       // 32 i32  (histp1 publishes)
#define OFF_FCNT   32                      // 32 i32
#define OFF_KREM1  64                      // 32 i32  (histp1 -> sel_mid)
#define OFF_PREF1  96                      // 32 u32
#define OFF_SCALE  128                     // 32 f32  (sel_mid -> main)
#define OFF_POSE   160                     // 32 f32  (sel_mid -> finalize)
#define OFF_PMF    192                     // 512*{i32 M,i32 F} = 1024 u32
#define OFF_PART   1216                    // 6144*5 f32 = 30720 u32
#define OFF_PHA    31936                   // 32*16*2048 u32 (hist0 partials)
#define OFF_PHB    (OFF_PHA + NIMG*HBLK*2048)   // 32*16*2048 u32 (histp1 partials)

__device__ __forceinline__ bool finitef(float x) {
    return ((__float_as_uint(x) >> 23) & 0xFFu) != 0xFFu;
}

// ======= pass 1: bits[31:21] hist partials + msum/fcnt (lean, r13-proven) =======
__global__ __launch_bounds__(HTHR) void hist0_k(
    const float* __restrict__ dp, const float* __restrict__ dg,
    const uint8_t* __restrict__ vmask, uint32_t* __restrict__ ws)
{
    __shared__ uint32_t lh[2048];
    __shared__ int sm[8], sf[8];
    const int img = blockIdx.y, blk = blockIdx.x, t = threadIdx.x;
    for (int b = t; b < 2048; b += HTHR) lh[b] = 0;
    __syncthreads();

    const size_t base = (size_t)img * HW_;
    const float* dpi = dp + base;
    const float* dgi = dg + base;
    const uint8_t* mi = vmask + base;

    int m2c = 0, fmc = 0;

    for (int c = 0; c < CITER; ++c) {
        const int pix = blk * PXB + c * (HTHR * 4) + t * 4;
        const float4 v_dp = *reinterpret_cast<const float4*>(dpi + pix);
        const float4 v_dg = *reinterpret_cast<const float4*>(dgi + pix);
        const uchar4 v_m  = *reinterpret_cast<const uchar4*>(mi + pix);
        const float dpa[4] = {v_dp.x, v_dp.y, v_dp.z, v_dp.w};
        const float dga[4] = {v_dg.x, v_dg.y, v_dg.z, v_dg.w};
        const uint8_t ma[4] = {v_m.x, v_m.y, v_m.z, v_m.w};
        int bins[4]; bool fms[4];
#pragma unroll
        for (int e = 0; e < 4; ++e) {
            const float dgv = dga[e], dpv = dpa[e];
            const bool vm = ma[e] && finitef(dgv) && (dgv > 1e-6f);
            const bool m2 = vm && finitef(dpv) && (dpv > EPSF);
            const float ratio = dpv / fmaxf(dgv, EPSF);
            const bool fm = m2 && finitef(ratio);
            m2c += (int)m2; fmc += (int)fm;
            const uint32_t key = fm ? __float_as_uint(ratio) : SENT;
            bins[e] = (int)(key >> 21);
            fms[e] = fm;
        }

        // wave-aggregated histogram add (few distinct bins -> few iterations)
#pragma unroll
        for (int e = 0; e < 4; ++e) {
            const bool fm = fms[e];
            const int bin = bins[e];
            unsigned long long todo = __ballot(fm);
            while (todo) {
                const int lead = (int)__ffsll(todo) - 1;
                const int lbin = __shfl(bin, lead);
                const unsigned long long same = __ballot(fm && (bin == lbin));
                if ((t & 63) == lead)
                    atomicAdd(&lh[lbin], (uint32_t)__popcll(same));
                todo &= ~same;
            }
        }
    }

    for (int o = 32; o > 0; o >>= 1) { m2c += __shfl_down(m2c, o); fmc += __shfl_down(fmc, o); }
    if ((t & 63) == 0) { sm[t >> 6] = m2c; sf[t >> 6] = fmc; }
    __syncthreads();
    if (t == 0) {
        int M = 0, F = 0;
        for (int w = 0; w < 8; ++w) { M += sm[w]; F += sf[w]; }
        int* pmf = (int*)(ws + OFF_PMF) + (img * HBLK + blk) * 2;
        pmf[0] = M; pmf[1] = F;
    }

    uint32_t* phb = ws + OFF_PHA + (size_t)(img * HBLK + blk) * 2048;
    for (int b = t; b < 2048; b += HTHR) phb[b] = lh[b];
}

// ======= pass 2: fused select of bits[31:21] + histogram of bits[20:10] (r13) =======
__global__ __launch_bounds__(HTHR) void histp1_k(
    const float* __restrict__ dp, const float* __restrict__ dg,
    const uint8_t* __restrict__ vmask, uint32_t* __restrict__ ws)
{
    __shared__ uint32_t lh[2048];
    __shared__ uint32_t wsum[8];
    __shared__ int s_bin, s_krem, s_msum, s_fcnt;
    const int img = blockIdx.y, blk = blockIdx.x, t = threadIdx.x;

    // ---- fused select prologue (every block computes identical result) ----
    const uint32_t* pin = ws + OFF_PHA + (size_t)img * HBLK * 2048;
    uint32_t local[4];
#pragma unroll
    for (int c = 0; c < 4; ++c) local[c] = 0;
    for (int b = 0; b < HBLK; ++b) {
        const uint32_t* row = pin + b * 2048 + t * 4;
#pragma unroll
        for (int c = 0; c < 4; ++c) local[c] += row[c];
    }
    const uint32_t cs = local[0] + local[1] + local[2] + local[3];

    uint32_t v = cs;
#pragma unroll
    for (int o = 1; o < 64; o <<= 1) {
        const uint32_t u = __shfl_up(v, o);
        if ((t & 63) >= o) v += u;
    }
    if ((t & 63) == 63) wsum[t >> 6] = v;
    if (t == 0) {
        s_bin = 0; s_krem = 0;
        const int* pmf = (const int*)(ws + OFF_PMF) + img * HBLK * 2;
        int M = 0, F = 0;
        for (int b = 0; b < HBLK; ++b) { M += pmf[2 * b]; F += pmf[2 * b + 1]; }
        s_msum = M; s_fcnt = F;
    }
    __syncthreads();
    uint32_t woff = 0;
    for (int w = 0; w < (t >> 6); ++w) woff += wsum[w];
    const uint32_t incl = woff + v;
    const uint32_t excl = incl - cs;

    const uint32_t k = (uint32_t)max((s_fcnt - 1) / 2, 0);
    if (k >= excl && k < incl) {
        uint32_t cum = excl;
#pragma unroll
        for (int c = 0; c < 4; ++c) {
            if (cum + local[c] > k) { s_bin = t * 4 + c; s_krem = (int)(k - cum); break; }
            cum += local[c];
        }
    }
    __syncthreads();
    if (t == 0 && blk == 0) {   // all blocks agree; one writer
        ((int*)(ws + OFF_MSUM))[img] = s_msum;
        ((int*)(ws + OFF_FCNT))[img] = s_fcnt;
        (ws + OFF_PREF1)[img] = (uint32_t)s_bin << 21;
        ((int*)(ws + OFF_KREM1))[img] = s_krem;
    }
    const uint32_t pm = (uint32_t)s_bin;   // prefix match on bits[31:21]

    // ---- histogram body: bits[20:10] of prefix-matched keys (recomputed) ----
    for (int b = t; b < 2048; b += HTHR) lh[b] = 0;
    __syncthreads();

    const size_t base = (size_t)img * HW_;
    for (int c = 0; c < CITER; ++c) {
        const int pix = blk * PXB + c * (HTHR * 4) + t * 4;
        const float4 v_dp = *reinterpret_cast<const float4*>(dp + base + pix);
        const float4 v_dg = *reinterpret_cast<const float4*>(dg + base + pix);
        const uchar4 v_m  = *reinterpret_cast<const uchar4*>(vmask + base + pix);
        const float dpa[4] = {v_dp.x, v_dp.y, v_dp.z, v_dp.w};
        const float dga[4] = {v_dg.x, v_dg.y, v_dg.z, v_dg.w};
        const uint8_t ma[4] = {v_m.x, v_m.y, v_m.z, v_m.w};
#pragma unroll
        for (int e = 0; e < 4; ++e) {
            const float dgv = dga[e], dpv = dpa[e];
            const bool vm = ma[e] && finitef(dgv) && (dgv > 1e-6f);
            const bool m2 = vm && finitef(dpv) && (dpv > EPSF);
            const float ratio = dpv / fmaxf(dgv, EPSF);
            const bool fm = m2 && finitef(ratio);
            const uint32_t key = fm ? __float_as_uint(ratio) : SENT;
            if ((key >> 21) == pm)
                atomicAdd(&lh[(key >> 10) & 2047u], 1u);
        }
    }
    __syncthreads();

    uint32_t* pout = ws + OFF_PHB + (size_t)(img * HBLK + blk) * 2048;
    for (int b = t; b < 2048; b += HTHR) pout[b] = lh[b];
}

// ======= final select: bits[20:10] bin -> median midpoint + scale + pose (r13) =======
__global__ __launch_bounds__(256) void sel_mid_k(
    uint32_t* __restrict__ ws,
    const float* __restrict__ intr, const float* __restrict__ posegt,
    const float* __restrict__ posepred)
{
    const int img = blockIdx.x;
    const int t = threadIdx.x;
    const uint32_t* ph = ws + OFF_PHB + (size_t)img * HBLK * 2048;
    uint32_t local[8];
#pragma unroll
    for (int c = 0; c < 8; ++c) local[c] = 0;
    for (int b = 0; b < HBLK; ++b) {
        const uint32_t* row = ph + b * 2048 + t * 8;
#pragma unroll
        for (int c = 0; c < 8; ++c) local[c] += row[c];
    }
    uint32_t cs = 0;
#pragma unroll
    for (int c = 0; c < 8; ++c) cs += local[c];

    __shared__ uint32_t wsum[4];
    __shared__ int s_bin;
    uint32_t v = cs;
#pragma unroll
    for (int o = 1; o < 64; o <<= 1) {
        const uint32_t u = __shfl_up(v, o);
        if ((t & 63) >= o) v += u;
    }
    if ((t & 63) == 63) wsum[t >> 6] = v;
    if (t == 0) s_bin = 0;
    __syncthreads();
    uint32_t woff = 0;
    for (int w = 0; w < (t >> 6); ++w) woff += wsum[w];
    const uint32_t incl = woff + v;
    const uint32_t excl = incl - cs;

    const uint32_t k = (uint32_t)((const int*)(ws + OFF_KREM1))[img];
    if (k >= excl && k < incl) {
        uint32_t cum = excl;
#pragma unroll
        for (int c = 0; c < 8; ++c) {
            if (cum + local[c] > k) { s_bin = t * 8 + c; break; }
            cum += local[c];
        }
    }
    __syncthreads();

    if (t == 0) {
        const uint32_t med_u = (ws + OFF_PREF1)[img] | ((uint32_t)s_bin << 10) | 512u;
        const float med = __uint_as_float(med_u);
        float sc_ = fminf(fmaxf(med, 0.001f), 1000.0f);
        const int fcnt = ((const int*)(ws + OFF_FCNT))[img];
        const int msum = ((const int*)(ws + OFF_MSUM))[img];
        if (msum < 16 || fcnt == 0) sc_ = 1.0f;
        ((float*)(ws + OFF_SCALE))[img] = sc_;

        const float* p = posegt + img * 16;
        const float m00 = p[0], m01 = p[1], m02 = p[2], tx = p[3];
        const float m10 = p[4], m11 = p[5], m12 = p[6], ty = p[7];
        const float m20 = p[8], m21 = p[9], m22 = p[10], tz = p[11];
        float qa[4];
        qa[0] = sqrtf(fmaxf(1.0f + m00 + m11 + m22, 0.0f));
        qa[1] = sqrtf(fmaxf(1.0f + m00 - m11 - m22, 0.0f));
        qa[2] = sqrtf(fmaxf(1.0f - m00 + m11 - m22, 0.0f));
        qa[3] = sqrtf(fmaxf(1.0f - m00 - m11 + m22, 0.0f));
        int best = 0; float bv = qa[0];
        for (int i2 = 1; i2 < 4; ++i2) if (qa[i2] > bv) { bv = qa[i2]; best = i2; }
        float c0, c1, c2, c3;
        if (best == 0)      { c0 = qa[0]*qa[0]; c1 = m21 - m12;   c2 = m02 - m20;   c3 = m10 - m01; }
        else if (best == 1) { c0 = m21 - m12;   c1 = qa[1]*qa[1]; c2 = m10 + m01;   c3 = m02 + m20; }
        else if (best == 2) { c0 = m02 - m20;   c1 = m10 + m01;   c2 = qa[2]*qa[2]; c3 = m12 + m21; }
        else                { c0 = m10 - m01;   c1 = m20 + m02;   c2 = m21 + m12;   c3 = qa[3]*qa[3]; }
        const float denom = 2.0f * fmaxf(qa[best], 0.1f);
        float q0 = c0 / denom, q1 = c1 / denom, q2 = c2 / denom, q3 = c3 / denom;
        if (q0 < 0.0f) { q0 = -q0; q1 = -q1; q2 = -q2; q3 = -q3; }
        const float fx = intr[img * 9 + 0], fy = intr[img * 9 + 4];
        const float fovh = 2.0f * atanf((H_ * 0.5f) / fy);
        const float fovw = 2.0f * atanf((W_ * 0.5f) / fx);
        const float pg[9] = {tx * sc_, ty * sc_, tz * sc_, q0, q1, q2, q3, fovh, fovw};
        const float* ppred = posepred + img * 9;
        float s = 0.0f;
        for (int i2 = 0; i2 < 9; ++i2) {
            const float d = fabsf(ppred[i2] - pg[i2]);
            s += (d < 1.0f) ? 0.5f * d * d : d - 0.5f;
        }
        ((float*)(ws + OFF_POSE))[img] = s;
    }
}

// ======= main loss: depth + points + normals, 4 px/thread, pts via LDS =======
// pts_pred is loaded UNIT-STRIDE (3 float4/thread at +1024-float offsets) into
// 12 KB LDS, then redistributed per-pixel -- fixes the 96B/lane-stride gather
// that throttled memory issue to ~1.75 TB/s (r14/r17 diagnosis).
__global__ __launch_bounds__(256) void main_loss(
    const float* __restrict__ dp, const float* __restrict__ dg,
    const uint8_t* __restrict__ vmask, const float* __restrict__ pts_pred,
    const float* __restrict__ intr, const float* __restrict__ posegt,
    uint32_t* __restrict__ ws)
{
    const int img = blockIdx.y;
    const int t = threadIdx.x;
    __shared__ __align__(16) float ptsLds[3072];    // 12 KB
    __shared__ float sP[17];

    const size_t base = (size_t)img * HW_;
    const int blk0 = blockIdx.x * 1024;             // first pixel of this block
    const float* dpi = dp + base;
    const float* dgi = dg + base;

    // ---- 1. issue coop pts loads (unit stride, fully coalesced) ----
    const float* psrc = pts_pred + (base + blk0) * 3;
    float4 pstg[3];
#pragma unroll
    for (int k = 0; k < 3; ++k)
        pstg[k] = *reinterpret_cast<const float4*>(psrc + 4 * (t + 256 * k));

    // ---- 2. issue pixel loads (center unit-stride; neighbor rows) ----
    const int pix0 = blk0 + t * 4;
    const int i = pix0 >> 9;
    const int j0 = pix0 & 511;
    const float4 v_dp = *reinterpret_cast<const float4*>(dpi + pix0);
    const float4 v_dg = *reinterpret_cast<const float4*>(dgi + pix0);
    const uchar4 v_m  = *reinterpret_cast<const uchar4*>(vmask + base + pix0);
    const int im = (i > 0) ? i - 1 : 0;
    const int ip = (i < H_ - 1) ? i + 1 : i;
    const int jme = (j0 > 0) ? j0 - 1 : 0;
    const int jpe = (j0 + 4 < W_) ? j0 + 4 : W_ - 1;
    const float4 dpU = *reinterpret_cast<const float4*>(dpi + im * W_ + j0);
    const float4 dpD = *reinterpret_cast<const float4*>(dpi + ip * W_ + j0);
    const float4 dgU = *reinterpret_cast<const float4*>(dgi + im * W_ + j0);
    const float4 dgD = *reinterpret_cast<const float4*>(dgi + ip * W_ + j0);
    const float dpLe = dpi[i * W_ + jme], dpRe = dpi[i * W_ + jpe];
    const float dgLe = dgi[i * W_ + jme], dgRe = dgi[i * W_ + jpe];

    if (t == 0) {
        const float* p = posegt + img * 16;
        sP[0] = p[0]; sP[1] = p[1]; sP[2] = p[2];  sP[9]  = p[3];
        sP[3] = p[4]; sP[4] = p[5]; sP[5] = p[6];  sP[10] = p[7];
        sP[6] = p[8]; sP[7] = p[9]; sP[8] = p[10]; sP[11] = p[11];
        sP[12] = intr[img * 9 + 0]; sP[13] = intr[img * 9 + 4];
        sP[14] = intr[img * 9 + 2]; sP[15] = intr[img * 9 + 5];
        sP[16] = ((const float*)(ws + OFF_SCALE))[img];
    }

    // ---- 3. stage pts into LDS, then read own 12 floats ----
#pragma unroll
    for (int k = 0; k < 3; ++k)
        *reinterpret_cast<float4*>(ptsLds + 4 * (t + 256 * k)) = pstg[k];
    __syncthreads();
    const float4 pq0 = *reinterpret_cast<const float4*>(ptsLds + 12 * t);
    const float4 pq1 = *reinterpret_cast<const float4*>(ptsLds + 12 * t + 4);
    const float4 pq2 = *reinterpret_cast<const float4*>(ptsLds + 12 * t + 8);

    const float R00 = sP[0], R01 = sP[1], R02 = sP[2];
    const float R10 = sP[3], R11 = sP[4], R12 = sP[5];
    const float R20 = sP[6], R21 = sP[7], R22 = sP[8];
    const float T0 = sP[9], T1 = sP[10], T2 = sP[11];
    const float inv_fx = 1.0f / fmaxf(sP[12], EPSF);
    const float inv_fy = 1.0f / fmaxf(sP[13], EPSF);
    const float cx = sP[14], cy = sP[15];
    const float sc = sP[16];

    const float ppv[12] = {pq0.x, pq0.y, pq0.z, pq0.w, pq1.x, pq1.y, pq1.z, pq1.w,
                           pq2.x, pq2.y, pq2.z, pq2.w};
    const float dpa[4] = {v_dp.x, v_dp.y, v_dp.z, v_dp.w};
    const float dga[4] = {v_dg.x, v_dg.y, v_dg.z, v_dg.w};
    const float dpUa[4] = {dpU.x, dpU.y, dpU.z, dpU.w};
    const float dpDa[4] = {dpD.x, dpD.y, dpD.z, dpD.w};
    const float dgUa[4] = {dgU.x, dgU.y, dgU.z, dgU.w};
    const float dgDa[4] = {dgD.x, dgD.y, dgD.z, dgD.w};
    const uint8_t ma[4] = {v_m.x, v_m.y, v_m.z, v_m.w};

    const float ay = ((float)i - cy) * inv_fy;
    const bool row_int = (i >= 1) && (i <= H_ - 2);

    float dsum = 0.0f, psum = 0.0f, nsum = 0.0f;
    float vcnt = 0.0f, ncnt = 0.0f;

#pragma unroll
    for (int e = 0; e < 4; ++e) {
        const int j = j0 + e;
        const float dgv = dga[e], dpv = dpa[e];
        const bool vm = ma[e] && finitef(dgv) && (dgv > 1e-6f);
        const bool nm = vm && row_int && (j >= 1) && (j <= W_ - 2);
        vcnt += vm ? 1.0f : 0.0f;
        ncnt += nm ? 1.0f : 0.0f;

        const float dal = dgv * sc;
        dsum += vm ? fabsf(dpv - dal) : 0.0f;
        const float ax = ((float)j - cx) * inv_fx;
        const float cxx = ax * dal, cyy = ay * dal;
        const float wx = R00 * cxx + R01 * cyy + R02 * dal + T0;
        const float wy = R10 * cxx + R11 * cyy + R12 * dal + T1;
        const float wz = R20 * cxx + R21 * cyy + R22 * dal + T2;
        const float pl = fabsf(ppv[3 * e] - wx) + fabsf(ppv[3 * e + 1] - wy)
                       + fabsf(ppv[3 * e + 2] - wz);
        psum += vm ? pl : 0.0f;

        const float pdL = (e == 0) ? dpLe : dpa[e - 1];
        const float pdR = (e == 3) ? dpRe : dpa[e + 1];
        const float gdL = (e == 0) ? dgLe : dga[e - 1];
        const float gdR = (e == 3) ? dgRe : dga[e + 1];
        const float pdU = dpUa[e], pdD = dpDa[e];
        const float gdU = dgUa[e], gdD = dgDa[e];

        // simplified cross algebra (r12-verified)
        const float dRLp = pdR - pdL, dDUp = pdD - pdU;
        const float Ap = inv_fy * (pdD + pdU);
        const float Bp = inv_fx * (pdR + pdL);
        const float cpx = dRLp * Ap;
        const float cpy = dDUp * Bp;
        const float cpz = -(Ap * Bp + ax * cpx + ay * cpy);
        const float dRLg = gdR - gdL, dDUg = gdD - gdU;
        const float Ag = inv_fy * (gdD + gdU);
        const float Bg = inv_fx * (gdR + gdL);
        const float cgx = dRLg * Ag;
        const float cgy = dDUg * Bg;
        const float cgz = -(Ag * Bg + ax * cgx + ay * cgy);

        const float np2 = cpx * cpx + cpy * cpy + cpz * cpz;
        const float ng2 = cgx * cgx + cgy * cgy + cgz * cgz;
        const float dpg = cpx * cgx + cpy * cgy + cpz * cgz;
        const float den = fmaxf(np2, 1e-12f) * fmaxf(ng2, 1e-12f);
        float cosv = dpg * __builtin_amdgcn_rsqf(den);
        cosv = fminf(fmaxf(cosv, -1.0f), 1.0f);
        nsum += nm ? (1.0f - cosv) : 0.0f;
    }

    float vals[5] = {vcnt, dsum, psum, nsum, ncnt};
    __shared__ float red[4][5];
    const int wave = t >> 6, lane = t & 63;
#pragma unroll
    for (int q = 0; q < 5; ++q) {
        float v = vals[q];
        for (int o = 32; o > 0; o >>= 1) v += __shfl_down(v, o);
        if (lane == 0) red[wave][q] = v;
    }
    __syncthreads();
    if (t == 0) {
        const int slot = blockIdx.y * gridDim.x + blockIdx.x;
        float* part = (float*)(ws + OFF_PART) + slot * 5;
#pragma unroll
        for (int q = 0; q < 5; ++q)
            part[q] = red[0][q] + red[1][q] + red[2][q] + red[3][q];
    }
}

// ======= finalize =======
__global__ __launch_bounds__(256) void finalize_k(const uint32_t* __restrict__ ws,
                                                  float* __restrict__ out)
{
    const float* part = (const float*)(ws + OFF_PART);
    const int t = threadIdx.x;
    double s[5] = {0, 0, 0, 0, 0};
    for (int slot = t; slot < NPARTS; slot += 256) {
#pragma unroll
        for (int q = 0; q < 5; ++q) s[q] += (double)part[slot * 5 + q];
    }
    __shared__ double red[4][5];
    const int wave = t >> 6, lane = t & 63;
#pragma unroll
    for (int q = 0; q < 5; ++q) {
        double v = s[q];
        for (int o = 32; o > 0; o >>= 1) v += __shfl_down(v, o);
        if (lane == 0) red[wave][q] = v;
    }
    __syncthreads();
    if (t == 0) {
        double tot[5];
#pragma unroll
        for (int q = 0; q < 5; ++q)
            tot[q] = red[0][q] + red[1][q] + red[2][q] + red[3][q];
        const float* pose = (const float*)(ws + OFF_POSE);
        double ps = 0.0;
        for (int i2 = 0; i2 < NIMG; ++i2) ps += (double)pose[i2];
        const double vmc = tot[0];
        const double depth_loss  = tot[1] / fmax(vmc, 1.0);
        const double points_loss = tot[2] / fmax(3.0 * vmc, 1.0);
        const double normal_loss = tot[3] / fmax(tot[4], 1.0);
        const double pose_loss   = ps / 288.0;
        out[0] = (float)(pose_loss + depth_loss + points_loss + 0.1 * normal_loss);
    }
}

extern "C" void kernel_launch(void* const* d_in, const int* in_sizes, int n_in,
                              void* d_out, int out_size, void* d_ws, size_t ws_size,
                              hipStream_t stream)
{
    const float*   dp       = (const float*)d_in[0];
    const float*   pts_pred = (const float*)d_in[1];
    const float*   posepred = (const float*)d_in[2];
    const float*   dg       = (const float*)d_in[3];
    const float*   intr     = (const float*)d_in[4];
    const float*   posegt   = (const float*)d_in[5];
    const uint8_t* vmask    = (const uint8_t*)d_in[6];
    float* out = (float*)d_out;
    uint32_t* ws = (uint32_t*)d_ws;

    const dim3 hgrid(HBLK, NIMG);
    hist0_k<<<hgrid, HTHR, 0, stream>>>(dp, dg, vmask, ws);
    histp1_k<<<hgrid, HTHR, 0, stream>>>(dp, dg, vmask, ws);
    sel_mid_k<<<NIMG, 256, 0, stream>>>(ws, intr, posegt, posepred);
    main_loss<<<dim3(MBLK, NIMG), 256, 0, stream>>>(dp, dg, vmask, pts_pred, intr, posegt, ws);
    finalize_k<<<1, 256, 0, stream>>>(ws, out);
}

// Round 19
// 62.764 us; speedup vs baseline: 1.1946x; 1.1946x over previous
//
#include <hip/hip_runtime.h>
#include <stdint.h>

#define H_ 384
#define W_ 512
#define HW_ (H_ * W_)
#define NIMG 32
#define EPSF 1e-6f
#define HBLK 16            // blocks per image (hist AND main)
#define HTHR 512           // threads per block
#define PXB (HW_ / HBLK)   // 12288 px per block
#define CITER (PXB / (HTHR * 4))  // 6
#define NPARTS (HBLK * NIMG)      // 512
#define SENT 0xFFFFFFFFu

// ---- workspace layout (u32 indices). NOTHING pre-zeroed; every buffer is ----
// ---- fully overwritten before read each call. No fences/done counters.   ----
#define OFF_MSUM   0                       // 32 i32  (histp1 publishes)
#define OFF_FCNT   32                      // 32 i32
#define OFF_KREM1  64                      // 32 i32  (histp1 -> sel_mid)
#define OFF_PREF1  96                      // 32 u32
#define OFF_SCALE  128                     // 32 f32  (sel_mid -> main)
#define OFF_POSE   160                     // 32 f32  (sel_mid -> finalize)
#define OFF_PMF    192                     // 512*{i32 M,i32 F} = 1024 u32
#define OFF_PART   1216                    // 512*5 f32 = 2560 u32
#define OFF_PHA    3776                    // 32*16*2048 u32 (hist0 partials)
#define OFF_PHB    (OFF_PHA + NIMG*HBLK*2048)   // 32*16*2048 u32 (histp1 partials)

__device__ __forceinline__ bool finitef(float x) {
    return ((__float_as_uint(x) >> 23) & 0xFFu) != 0xFFu;
}

// ======= pass 1: bits[31:21] hist partials + msum/fcnt (lean, r13-proven) =======
__global__ __launch_bounds__(HTHR) void hist0_k(
    const float* __restrict__ dp, const float* __restrict__ dg,
    const uint8_t* __restrict__ vmask, uint32_t* __restrict__ ws)
{
    __shared__ uint32_t lh[2048];
    __shared__ int sm[8], sf[8];
    const int img = blockIdx.y, blk = blockIdx.x, t = threadIdx.x;
    for (int b = t; b < 2048; b += HTHR) lh[b] = 0;
    __syncthreads();

    const size_t base = (size_t)img * HW_;
    const float* dpi = dp + base;
    const float* dgi = dg + base;
    const uint8_t* mi = vmask + base;

    int m2c = 0, fmc = 0;

    for (int c = 0; c < CITER; ++c) {
        const int pix = blk * PXB + c * (HTHR * 4) + t * 4;
        const float4 v_dp = *reinterpret_cast<const float4*>(dpi + pix);
        const float4 v_dg = *reinterpret_cast<const float4*>(dgi + pix);
        const uchar4 v_m  = *reinterpret_cast<const uchar4*>(mi + pix);
        const float dpa[4] = {v_dp.x, v_dp.y, v_dp.z, v_dp.w};
        const float dga[4] = {v_dg.x, v_dg.y, v_dg.z, v_dg.w};
        const uint8_t ma[4] = {v_m.x, v_m.y, v_m.z, v_m.w};
        int bins[4]; bool fms[4];
#pragma unroll
        for (int e = 0; e < 4; ++e) {
            const float dgv = dga[e], dpv = dpa[e];
            const bool vm = ma[e] && finitef(dgv) && (dgv > 1e-6f);
            const bool m2 = vm && finitef(dpv) && (dpv > EPSF);
            const float ratio = dpv / fmaxf(dgv, EPSF);
            const bool fm = m2 && finitef(ratio);
            m2c += (int)m2; fmc += (int)fm;
            const uint32_t key = fm ? __float_as_uint(ratio) : SENT;
            bins[e] = (int)(key >> 21);
            fms[e] = fm;
        }

        // wave-aggregated histogram add (few distinct bins -> few iterations)
#pragma unroll
        for (int e = 0; e < 4; ++e) {
            const bool fm = fms[e];
            const int bin = bins[e];
            unsigned long long todo = __ballot(fm);
            while (todo) {
                const int lead = (int)__ffsll(todo) - 1;
                const int lbin = __shfl(bin, lead);
                const unsigned long long same = __ballot(fm && (bin == lbin));
                if ((t & 63) == lead)
                    atomicAdd(&lh[lbin], (uint32_t)__popcll(same));
                todo &= ~same;
            }
        }
    }

    for (int o = 32; o > 0; o >>= 1) { m2c += __shfl_down(m2c, o); fmc += __shfl_down(fmc, o); }
    if ((t & 63) == 0) { sm[t >> 6] = m2c; sf[t >> 6] = fmc; }
    __syncthreads();
    if (t == 0) {
        int M = 0, F = 0;
        for (int w = 0; w < 8; ++w) { M += sm[w]; F += sf[w]; }
        int* pmf = (int*)(ws + OFF_PMF) + (img * HBLK + blk) * 2;
        pmf[0] = M; pmf[1] = F;
    }

    uint32_t* phb = ws + OFF_PHA + (size_t)(img * HBLK + blk) * 2048;
    for (int b = t; b < 2048; b += HTHR) phb[b] = lh[b];
}

// ======= pass 2: fused select of bits[31:21] + histogram of bits[20:10] (r13) =======
__global__ __launch_bounds__(HTHR) void histp1_k(
    const float* __restrict__ dp, const float* __restrict__ dg,
    const uint8_t* __restrict__ vmask, uint32_t* __restrict__ ws)
{
    __shared__ uint32_t lh[2048];
    __shared__ uint32_t wsum[8];
    __shared__ int s_bin, s_krem, s_msum, s_fcnt;
    const int img = blockIdx.y, blk = blockIdx.x, t = threadIdx.x;

    // ---- fused select prologue (every block computes identical result) ----
    const uint32_t* pin = ws + OFF_PHA + (size_t)img * HBLK * 2048;
    uint32_t local[4];
#pragma unroll
    for (int c = 0; c < 4; ++c) local[c] = 0;
    for (int b = 0; b < HBLK; ++b) {
        const uint32_t* row = pin + b * 2048 + t * 4;
#pragma unroll
        for (int c = 0; c < 4; ++c) local[c] += row[c];
    }
    const uint32_t cs = local[0] + local[1] + local[2] + local[3];

    uint32_t v = cs;
#pragma unroll
    for (int o = 1; o < 64; o <<= 1) {
        const uint32_t u = __shfl_up(v, o);
        if ((t & 63) >= o) v += u;
    }
    if ((t & 63) == 63) wsum[t >> 6] = v;
    if (t == 0) {
        s_bin = 0; s_krem = 0;
        const int* pmf = (const int*)(ws + OFF_PMF) + img * HBLK * 2;
        int M = 0, F = 0;
        for (int b = 0; b < HBLK; ++b) { M += pmf[2 * b]; F += pmf[2 * b + 1]; }
        s_msum = M; s_fcnt = F;
    }
    __syncthreads();
    uint32_t woff = 0;
    for (int w = 0; w < (t >> 6); ++w) woff += wsum[w];
    const uint32_t incl = woff + v;
    const uint32_t excl = incl - cs;

    const uint32_t k = (uint32_t)max((s_fcnt - 1) / 2, 0);
    if (k >= excl && k < incl) {
        uint32_t cum = excl;
#pragma unroll
        for (int c = 0; c < 4; ++c) {
            if (cum + local[c] > k) { s_bin = t * 4 + c; s_krem = (int)(k - cum); break; }
            cum += local[c];
        }
    }
    __syncthreads();
    if (t == 0 && blk == 0) {   // all blocks agree; one writer
        ((int*)(ws + OFF_MSUM))[img] = s_msum;
        ((int*)(ws + OFF_FCNT))[img] = s_fcnt;
        (ws + OFF_PREF1)[img] = (uint32_t)s_bin << 21;
        ((int*)(ws + OFF_KREM1))[img] = s_krem;
    }
    const uint32_t pm = (uint32_t)s_bin;   // prefix match on bits[31:21]

    // ---- histogram body: bits[20:10] of prefix-matched keys (recomputed) ----
    for (int b = t; b < 2048; b += HTHR) lh[b] = 0;
    __syncthreads();

    const size_t base = (size_t)img * HW_;
    for (int c = 0; c < CITER; ++c) {
        const int pix = blk * PXB + c * (HTHR * 4) + t * 4;
        const float4 v_dp = *reinterpret_cast<const float4*>(dp + base + pix);
        const float4 v_dg = *reinterpret_cast<const float4*>(dg + base + pix);
        const uchar4 v_m  = *reinterpret_cast<const uchar4*>(vmask + base + pix);
        const float dpa[4] = {v_dp.x, v_dp.y, v_dp.z, v_dp.w};
        const float dga[4] = {v_dg.x, v_dg.y, v_dg.z, v_dg.w};
        const uint8_t ma[4] = {v_m.x, v_m.y, v_m.z, v_m.w};
#pragma unroll
        for (int e = 0; e < 4; ++e) {
            const float dgv = dga[e], dpv = dpa[e];
            const bool vm = ma[e] && finitef(dgv) && (dgv > 1e-6f);
            const bool m2 = vm && finitef(dpv) && (dpv > EPSF);
            const float ratio = dpv / fmaxf(dgv, EPSF);
            const bool fm = m2 && finitef(ratio);
            const uint32_t key = fm ? __float_as_uint(ratio) : SENT;
            if ((key >> 21) == pm)
                atomicAdd(&lh[(key >> 10) & 2047u], 1u);
        }
    }
    __syncthreads();

    uint32_t* pout = ws + OFF_PHB + (size_t)(img * HBLK + blk) * 2048;
    for (int b = t; b < 2048; b += HTHR) pout[b] = lh[b];
}

// ======= final select: bits[20:10] bin -> median midpoint + scale + pose (r13) =======
__global__ __launch_bounds__(256) void sel_mid_k(
    uint32_t* __restrict__ ws,
    const float* __restrict__ intr, const float* __restrict__ posegt,
    const float* __restrict__ posepred)
{
    const int img = blockIdx.x;
    const int t = threadIdx.x;
    const uint32_t* ph = ws + OFF_PHB + (size_t)img * HBLK * 2048;
    uint32_t local[8];
#pragma unroll
    for (int c = 0; c < 8; ++c) local[c] = 0;
    for (int b = 0; b < HBLK; ++b) {
        const uint32_t* row = ph + b * 2048 + t * 8;
#pragma unroll
        for (int c = 0; c < 8; ++c) local[c] += row[c];
    }
    uint32_t cs = 0;
#pragma unroll
    for (int c = 0; c < 8; ++c) cs += local[c];

    __shared__ uint32_t wsum[4];
    __shared__ int s_bin;
    uint32_t v = cs;
#pragma unroll
    for (int o = 1; o < 64; o <<= 1) {
        const uint32_t u = __shfl_up(v, o);
        if ((t & 63) >= o) v += u;
    }
    if ((t & 63) == 63) wsum[t >> 6] = v;
    if (t == 0) s_bin = 0;
    __syncthreads();
    uint32_t woff = 0;
    for (int w = 0; w < (t >> 6); ++w) woff += wsum[w];
    const uint32_t incl = woff + v;
    const uint32_t excl = incl - cs;

    const uint32_t k = (uint32_t)((const int*)(ws + OFF_KREM1))[img];
    if (k >= excl && k < incl) {
        uint32_t cum = excl;
#pragma unroll
        for (int c = 0; c < 8; ++c) {
            if (cum + local[c] > k) { s_bin = t * 8 + c; break; }
            cum += local[c];
        }
    }
    __syncthreads();

    if (t == 0) {
        const uint32_t med_u = (ws + OFF_PREF1)[img] | ((uint32_t)s_bin << 10) | 512u;
        const float med = __uint_as_float(med_u);
        float sc_ = fminf(fmaxf(med, 0.001f), 1000.0f);
        const int fcnt = ((const int*)(ws + OFF_FCNT))[img];
        const int msum = ((const int*)(ws + OFF_MSUM))[img];
        if (msum < 16 || fcnt == 0) sc_ = 1.0f;
        ((float*)(ws + OFF_SCALE))[img] = sc_;

        const float* p = posegt + img * 16;
        const float m00 = p[0], m01 = p[1], m02 = p[2], tx = p[3];
        const float m10 = p[4], m11 = p[5], m12 = p[6], ty = p[7];
        const float m20 = p[8], m21 = p[9], m22 = p[10], tz = p[11];
        float qa[4];
        qa[0] = sqrtf(fmaxf(1.0f + m00 + m11 + m22, 0.0f));
        qa[1] = sqrtf(fmaxf(1.0f + m00 - m11 - m22, 0.0f));
        qa[2] = sqrtf(fmaxf(1.0f - m00 + m11 - m22, 0.0f));
        qa[3] = sqrtf(fmaxf(1.0f - m00 - m11 + m22, 0.0f));
        int best = 0; float bv = qa[0];
        for (int i2 = 1; i2 < 4; ++i2) if (qa[i2] > bv) { bv = qa[i2]; best = i2; }
        float c0, c1, c2, c3;
        if (best == 0)      { c0 = qa[0]*qa[0]; c1 = m21 - m12;   c2 = m02 - m20;   c3 = m10 - m01; }
        else if (best == 1) { c0 = m21 - m12;   c1 = qa[1]*qa[1]; c2 = m10 + m01;   c3 = m02 + m20; }
        else if (best == 2) { c0 = m02 - m20;   c1 = m10 + m01;   c2 = qa[2]*qa[2]; c3 = m12 + m21; }
        else                { c0 = m10 - m01;   c1 = m20 + m02;   c2 = m21 + m12;   c3 = qa[3]*qa[3]; }
        const float denom = 2.0f * fmaxf(qa[best], 0.1f);
        float q0 = c0 / denom, q1 = c1 / denom, q2 = c2 / denom, q3 = c3 / denom;
        if (q0 < 0.0f) { q0 = -q0; q1 = -q1; q2 = -q2; q3 = -q3; }
        const float fx = intr[img * 9 + 0], fy = intr[img * 9 + 4];
        const float fovh = 2.0f * atanf((H_ * 0.5f) / fy);
        const float fovw = 2.0f * atanf((W_ * 0.5f) / fx);
        const float pg[9] = {tx * sc_, ty * sc_, tz * sc_, q0, q1, q2, q3, fovh, fovw};
        const float* ppred = posepred + img * 9;
        float s = 0.0f;
        for (int i2 = 0; i2 < 9; ++i2) {
            const float d = fabsf(ppred[i2] - pg[i2]);
            s += (d < 1.0f) ? 0.5f * d * d : d - 0.5f;
        }
        ((float*)(ws + OFF_POSE))[img] = s;
    }
}

// ======= main loss: hist0-SHAPED (512 thr, grid 16x32, 6-iter loop) =======
// All loss math (depth + points + normals). Long-lived blocks (2/CU) with a
// persistent loop let wave TLP hide load latency like the 6 TB/s hist kernels;
// one-shot 256-thread tiles plateaued at ~44 us across r13-r18.
__global__ __launch_bounds__(HTHR) void main_loss(
    const float* __restrict__ dp, const float* __restrict__ dg,
    const uint8_t* __restrict__ vmask, const float* __restrict__ pts_pred,
    const float* __restrict__ intr, const float* __restrict__ posegt,
    uint32_t* __restrict__ ws)
{
    const int img = blockIdx.y, blk = blockIdx.x, t = threadIdx.x;
    __shared__ float sP[17];
    if (t == 0) {
        const float* p = posegt + img * 16;
        sP[0] = p[0]; sP[1] = p[1]; sP[2] = p[2];  sP[9]  = p[3];
        sP[3] = p[4]; sP[4] = p[5]; sP[5] = p[6];  sP[10] = p[7];
        sP[6] = p[8]; sP[7] = p[9]; sP[8] = p[10]; sP[11] = p[11];
        sP[12] = intr[img * 9 + 0]; sP[13] = intr[img * 9 + 4];
        sP[14] = intr[img * 9 + 2]; sP[15] = intr[img * 9 + 5];
        sP[16] = ((const float*)(ws + OFF_SCALE))[img];
    }
    __syncthreads();
    const float R00 = sP[0], R01 = sP[1], R02 = sP[2];
    const float R10 = sP[3], R11 = sP[4], R12 = sP[5];
    const float R20 = sP[6], R21 = sP[7], R22 = sP[8];
    const float T0 = sP[9], T1 = sP[10], T2 = sP[11];
    const float inv_fx = 1.0f / fmaxf(sP[12], EPSF);
    const float inv_fy = 1.0f / fmaxf(sP[13], EPSF);
    const float cx = sP[14], cy = sP[15];
    const float sc = sP[16];

    const size_t base = (size_t)img * HW_;
    const float* dpi = dp + base;
    const float* dgi = dg + base;

    float dsum = 0.0f, psum = 0.0f, nsum = 0.0f;
    float vcnt = 0.0f, ncnt = 0.0f;

    for (int c = 0; c < CITER; ++c) {
        const int pix = blk * PXB + c * (HTHR * 4) + t * 4;
        const int i = pix >> 9;
        const int j0 = pix & 511;

        const float4 v_dp = *reinterpret_cast<const float4*>(dpi + pix);
        const float4 v_dg = *reinterpret_cast<const float4*>(dgi + pix);
        const uchar4 v_m  = *reinterpret_cast<const uchar4*>(vmask + base + pix);
        const float4 pp0 = *reinterpret_cast<const float4*>(pts_pred + (base + pix) * 3);
        const float4 pp1 = *reinterpret_cast<const float4*>(pts_pred + (base + pix) * 3 + 4);
        const float4 pp2 = *reinterpret_cast<const float4*>(pts_pred + (base + pix) * 3 + 8);

        const int im = (i > 0) ? i - 1 : 0;
        const int ip = (i < H_ - 1) ? i + 1 : i;
        const int jme = (j0 > 0) ? j0 - 1 : 0;
        const int jpe = (j0 + 4 < W_) ? j0 + 4 : W_ - 1;
        const float4 dpU = *reinterpret_cast<const float4*>(dpi + im * W_ + j0);
        const float4 dpD = *reinterpret_cast<const float4*>(dpi + ip * W_ + j0);
        const float4 dgU = *reinterpret_cast<const float4*>(dgi + im * W_ + j0);
        const float4 dgD = *reinterpret_cast<const float4*>(dgi + ip * W_ + j0);
        const float dpLe = dpi[i * W_ + jme], dpRe = dpi[i * W_ + jpe];
        const float dgLe = dgi[i * W_ + jme], dgRe = dgi[i * W_ + jpe];

        const float ppv[12] = {pp0.x, pp0.y, pp0.z, pp0.w, pp1.x, pp1.y, pp1.z, pp1.w,
                               pp2.x, pp2.y, pp2.z, pp2.w};
        const float dpa[4] = {v_dp.x, v_dp.y, v_dp.z, v_dp.w};
        const float dga[4] = {v_dg.x, v_dg.y, v_dg.z, v_dg.w};
        const float dpUa[4] = {dpU.x, dpU.y, dpU.z, dpU.w};
        const float dpDa[4] = {dpD.x, dpD.y, dpD.z, dpD.w};
        const float dgUa[4] = {dgU.x, dgU.y, dgU.z, dgU.w};
        const float dgDa[4] = {dgD.x, dgD.y, dgD.z, dgD.w};
        const uint8_t ma[4] = {v_m.x, v_m.y, v_m.z, v_m.w};

        const float ay = ((float)i - cy) * inv_fy;
        const bool row_int = (i >= 1) && (i <= H_ - 2);

#pragma unroll
        for (int e = 0; e < 4; ++e) {
            const int j = j0 + e;
            const float dgv = dga[e], dpv = dpa[e];
            const bool vm = ma[e] && finitef(dgv) && (dgv > 1e-6f);
            const bool nm = vm && row_int && (j >= 1) && (j <= W_ - 2);
            vcnt += vm ? 1.0f : 0.0f;
            ncnt += nm ? 1.0f : 0.0f;

            const float dal = dgv * sc;
            dsum += vm ? fabsf(dpv - dal) : 0.0f;
            const float ax = ((float)j - cx) * inv_fx;
            const float cxx = ax * dal, cyy = ay * dal;
            const float wx = R00 * cxx + R01 * cyy + R02 * dal + T0;
            const float wy = R10 * cxx + R11 * cyy + R12 * dal + T1;
            const float wz = R20 * cxx + R21 * cyy + R22 * dal + T2;
            const float pl = fabsf(ppv[3 * e] - wx) + fabsf(ppv[3 * e + 1] - wy)
                           + fabsf(ppv[3 * e + 2] - wz);
            psum += vm ? pl : 0.0f;

            const float pdL = (e == 0) ? dpLe : dpa[e - 1];
            const float pdR = (e == 3) ? dpRe : dpa[e + 1];
            const float gdL = (e == 0) ? dgLe : dga[e - 1];
            const float gdR = (e == 3) ? dgRe : dga[e + 1];
            const float pdU = dpUa[e], pdD = dpDa[e];
            const float gdU = dgUa[e], gdD = dgDa[e];

            // simplified cross algebra (r12-verified)
            const float dRLp = pdR - pdL, dDUp = pdD - pdU;
            const float Ap = inv_fy * (pdD + pdU);
            const float Bp = inv_fx * (pdR + pdL);
            const float cpx = dRLp * Ap;
            const float cpy = dDUp * Bp;
            const float cpz = -(Ap * Bp + ax * cpx + ay * cpy);
            const float dRLg = gdR - gdL, dDUg = gdD - gdU;
            const float Ag = inv_fy * (gdD + gdU);
            const float Bg = inv_fx * (gdR + gdL);
            const float cgx = dRLg * Ag;
            const float cgy = dDUg * Bg;
            const float cgz = -(Ag * Bg + ax * cgx + ay * cgy);

            const float np2 = cpx * cpx + cpy * cpy + cpz * cpz;
            const float ng2 = cgx * cgx + cgy * cgy + cgz * cgz;
            const float dpg = cpx * cgx + cpy * cgy + cpz * cgz;
            const float den = fmaxf(np2, 1e-12f) * fmaxf(ng2, 1e-12f);
            float cosv = dpg * __builtin_amdgcn_rsqf(den);
            cosv = fminf(fmaxf(cosv, -1.0f), 1.0f);
            nsum += nm ? (1.0f - cosv) : 0.0f;
        }
    }

    float vals[5] = {vcnt, dsum, psum, nsum, ncnt};
    __shared__ float red[8][5];
    const int wave = t >> 6, lane = t & 63;
#pragma unroll
    for (int q = 0; q < 5; ++q) {
        float v = vals[q];
        for (int o = 32; o > 0; o >>= 1) v += __shfl_down(v, o);
        if (lane == 0) red[wave][q] = v;
    }
    __syncthreads();
    if (t == 0) {
        const int slot = img * HBLK + blk;
        float* part = (float*)(ws + OFF_PART) + slot * 5;
#pragma unroll
        for (int q = 0; q < 5; ++q) {
            float s = 0.0f;
            for (int w = 0; w < 8; ++w) s += red[w][q];
            part[q] = s;
        }
    }
}

// ======= finalize =======
__global__ __launch_bounds__(256) void finalize_k(const uint32_t* __restrict__ ws,
                                                  float* __restrict__ out)
{
    const float* part = (const float*)(ws + OFF_PART);
    const int t = threadIdx.x;
    double s[5] = {0, 0, 0, 0, 0};
    for (int slot = t; slot < NPARTS; slot += 256) {
#pragma unroll
        for (int q = 0; q < 5; ++q) s[q] += (double)part[slot * 5 + q];
    }
    __shared__ double red[4][5];
    const int wave = t >> 6, lane = t & 63;
#pragma unroll
    for (int q = 0; q < 5; ++q) {
        double v = s[q];
        for (int o = 32; o > 0; o >>= 1) v += __shfl_down(v, o);
        if (lane == 0) red[wave][q] = v;
    }
    __syncthreads();
    if (t == 0) {
        double tot[5];
#pragma unroll
        for (int q = 0; q < 5; ++q)
            tot[q] = red[0][q] + red[1][q] + red[2][q] + red[3][q];
        const float* pose = (const float*)(ws + OFF_POSE);
        double ps = 0.0;
        for (int i2 = 0; i2 < NIMG; ++i2) ps += (double)pose[i2];
        const double vmc = tot[0];
        const double depth_loss  = tot[1] / fmax(vmc, 1.0);
        const double points_loss = tot[2] / fmax(3.0 * vmc, 1.0);
        const double normal_loss = tot[3] / fmax(tot[4], 1.0);
        const double pose_loss   = ps / 288.0;
        out[0] = (float)(pose_loss + depth_loss + points_loss + 0.1 * normal_loss);
    }
}

extern "C" void kernel_launch(void* const* d_in, const int* in_sizes, int n_in,
                              void* d_out, int out_size, void* d_ws, size_t ws_size,
                              hipStream_t stream)
{
    const float*   dp       = (const float*)d_in[0];
    const float*   pts_pred = (const float*)d_in[1];
    const float*   posepred = (const float*)d_in[2];
    const float*   dg       = (const float*)d_in[3];
    const float*   intr     = (const float*)d_in[4];
    const float*   posegt   = (const float*)d_in[5];
    const uint8_t* vmask    = (const uint8_t*)d_in[6];
    float* out = (float*)d_out;
    uint32_t* ws = (uint32_t*)d_ws;

    const dim3 hgrid(HBLK, NIMG);
    hist0_k<<<hgrid, HTHR, 0, stream>>>(dp, dg, vmask, ws);
    histp1_k<<<hgrid, HTHR, 0, stream>>>(dp, dg, vmask, ws);
    sel_mid_k<<<NIMG, 256, 0, stream>>>(ws, intr, posegt, posepred);
    main_loss<<<hgrid, HTHR, 0, stream>>>(dp, dg, vmask, pts_pred, intr, posegt, ws);
    finalize_k<<<1, 256, 0, stream>>>(ws, out);
}

// Round 20
// 59.037 us; speedup vs baseline: 1.2700x; 1.0631x over previous
//
#include <hip/hip_runtime.h>
#include <stdint.h>

#define H_ 384
#define W_ 512
#define HW_ (H_ * W_)
#define NIMG 32
#define EPSF 1e-6f
#define HBLK 16            // blocks per image (hist AND main)
#define HTHR 512           // threads per block
#define PXB (HW_ / HBLK)   // 12288 px per block
#define CITER (PXB / (HTHR * 4))  // 6
#define NPARTS (HBLK * NIMG)      // 512
#define SENT 0xFFFFFFFFu

// ---- workspace layout (u32 indices). NOTHING pre-zeroed; every buffer is ----
// ---- fully overwritten before read each call. No fences/done counters.   ----
// ---- r20: sel_mid deleted; 256-bin final hist; select replicated in main.----
#define OFF_MSUM   0                       // 32 i32  (histp1 publishes)
#define OFF_FCNT   32                      // 32 i32
#define OFF_KREM1  64                      // 32 i32  (histp1 -> main prologue)
#define OFF_PREF1  96                      // 32 u32
#define OFF_POSE   128                     // 32 f32  (main blk0 -> finalize)
#define OFF_PMF    160                     // 512*{i32 M,i32 F} = 1024 u32
#define OFF_PART   1184                    // 512*5 f32 = 2560 u32
#define OFF_PHA    3744                    // 32*16*2048 u32 (hist0 partials)
#define OFF_PHB    (OFF_PHA + NIMG*HBLK*2048)   // 32*16*256 u32 (histp1 partials)

__device__ __forceinline__ bool finitef(float x) {
    return ((__float_as_uint(x) >> 23) & 0xFFu) != 0xFFu;
}

// ======= pass 1: bits[31:21] hist partials + msum/fcnt (lean, r13-proven) =======
__global__ __launch_bounds__(HTHR) void hist0_k(
    const float* __restrict__ dp, const float* __restrict__ dg,
    const uint8_t* __restrict__ vmask, uint32_t* __restrict__ ws)
{
    __shared__ uint32_t lh[2048];
    __shared__ int sm[8], sf[8];
    const int img = blockIdx.y, blk = blockIdx.x, t = threadIdx.x;
    for (int b = t; b < 2048; b += HTHR) lh[b] = 0;
    __syncthreads();

    const size_t base = (size_t)img * HW_;
    const float* dpi = dp + base;
    const float* dgi = dg + base;
    const uint8_t* mi = vmask + base;

    int m2c = 0, fmc = 0;

    for (int c = 0; c < CITER; ++c) {
        const int pix = blk * PXB + c * (HTHR * 4) + t * 4;
        const float4 v_dp = *reinterpret_cast<const float4*>(dpi + pix);
        const float4 v_dg = *reinterpret_cast<const float4*>(dgi + pix);
        const uchar4 v_m  = *reinterpret_cast<const uchar4*>(mi + pix);
        const float dpa[4] = {v_dp.x, v_dp.y, v_dp.z, v_dp.w};
        const float dga[4] = {v_dg.x, v_dg.y, v_dg.z, v_dg.w};
        const uint8_t ma[4] = {v_m.x, v_m.y, v_m.z, v_m.w};
        int bins[4]; bool fms[4];
#pragma unroll
        for (int e = 0; e < 4; ++e) {
            const float dgv = dga[e], dpv = dpa[e];
            const bool vm = ma[e] && finitef(dgv) && (dgv > 1e-6f);
            const bool m2 = vm && finitef(dpv) && (dpv > EPSF);
            const float ratio = dpv / fmaxf(dgv, EPSF);
            const bool fm = m2 && finitef(ratio);
            m2c += (int)m2; fmc += (int)fm;
            const uint32_t key = fm ? __float_as_uint(ratio) : SENT;
            bins[e] = (int)(key >> 21);
            fms[e] = fm;
        }

        // wave-aggregated histogram add (few distinct bins -> few iterations)
#pragma unroll
        for (int e = 0; e < 4; ++e) {
            const bool fm = fms[e];
            const int bin = bins[e];
            unsigned long long todo = __ballot(fm);
            while (todo) {
                const int lead = (int)__ffsll(todo) - 1;
                const int lbin = __shfl(bin, lead);
                const unsigned long long same = __ballot(fm && (bin == lbin));
                if ((t & 63) == lead)
                    atomicAdd(&lh[lbin], (uint32_t)__popcll(same));
                todo &= ~same;
            }
        }
    }

    for (int o = 32; o > 0; o >>= 1) { m2c += __shfl_down(m2c, o); fmc += __shfl_down(fmc, o); }
    if ((t & 63) == 0) { sm[t >> 6] = m2c; sf[t >> 6] = fmc; }
    __syncthreads();
    if (t == 0) {
        int M = 0, F = 0;
        for (int w = 0; w < 8; ++w) { M += sm[w]; F += sf[w]; }
        int* pmf = (int*)(ws + OFF_PMF) + (img * HBLK + blk) * 2;
        pmf[0] = M; pmf[1] = F;
    }

    uint32_t* phb = ws + OFF_PHA + (size_t)(img * HBLK + blk) * 2048;
    for (int b = t; b < 2048; b += HTHR) phb[b] = lh[b];
}

// ======= pass 2: fused select of bits[31:21] + 256-bin hist of bits[20:13] =======
__global__ __launch_bounds__(HTHR) void histp1_k(
    const float* __restrict__ dp, const float* __restrict__ dg,
    const uint8_t* __restrict__ vmask, uint32_t* __restrict__ ws)
{
    __shared__ uint32_t lh[2048];
    __shared__ uint32_t wsum[8];
    __shared__ int s_bin, s_krem, s_msum, s_fcnt;
    const int img = blockIdx.y, blk = blockIdx.x, t = threadIdx.x;

    // ---- fused select prologue (every block computes identical result) ----
    const uint32_t* pin = ws + OFF_PHA + (size_t)img * HBLK * 2048;
    uint32_t local[4];
#pragma unroll
    for (int c = 0; c < 4; ++c) local[c] = 0;
    for (int b = 0; b < HBLK; ++b) {
        const uint32_t* row = pin + b * 2048 + t * 4;
#pragma unroll
        for (int c = 0; c < 4; ++c) local[c] += row[c];
    }
    const uint32_t cs = local[0] + local[1] + local[2] + local[3];

    uint32_t v = cs;
#pragma unroll
    for (int o = 1; o < 64; o <<= 1) {
        const uint32_t u = __shfl_up(v, o);
        if ((t & 63) >= o) v += u;
    }
    if ((t & 63) == 63) wsum[t >> 6] = v;
    if (t == 0) {
        s_bin = 0; s_krem = 0;
        const int* pmf = (const int*)(ws + OFF_PMF) + img * HBLK * 2;
        int M = 0, F = 0;
        for (int b = 0; b < HBLK; ++b) { M += pmf[2 * b]; F += pmf[2 * b + 1]; }
        s_msum = M; s_fcnt = F;
    }
    __syncthreads();
    uint32_t woff = 0;
    for (int w = 0; w < (t >> 6); ++w) woff += wsum[w];
    const uint32_t incl = woff + v;
    const uint32_t excl = incl - cs;

    const uint32_t k = (uint32_t)max((s_fcnt - 1) / 2, 0);
    if (k >= excl && k < incl) {
        uint32_t cum = excl;
#pragma unroll
        for (int c = 0; c < 4; ++c) {
            if (cum + local[c] > k) { s_bin = t * 4 + c; s_krem = (int)(k - cum); break; }
            cum += local[c];
        }
    }
    __syncthreads();
    if (t == 0 && blk == 0) {   // all blocks agree; one writer
        ((int*)(ws + OFF_MSUM))[img] = s_msum;
        ((int*)(ws + OFF_FCNT))[img] = s_fcnt;
        (ws + OFF_PREF1)[img] = (uint32_t)s_bin << 21;
        ((int*)(ws + OFF_KREM1))[img] = s_krem;
    }
    const uint32_t pm = (uint32_t)s_bin;   // prefix match on bits[31:21]

    // ---- histogram body: bits[20:13] of prefix-matched keys (256 bins) ----
    if (t < 256) lh[t] = 0;
    __syncthreads();

    const size_t base = (size_t)img * HW_;
    for (int c = 0; c < CITER; ++c) {
        const int pix = blk * PXB + c * (HTHR * 4) + t * 4;
        const float4 v_dp = *reinterpret_cast<const float4*>(dp + base + pix);
        const float4 v_dg = *reinterpret_cast<const float4*>(dg + base + pix);
        const uchar4 v_m  = *reinterpret_cast<const uchar4*>(vmask + base + pix);
        const float dpa[4] = {v_dp.x, v_dp.y, v_dp.z, v_dp.w};
        const float dga[4] = {v_dg.x, v_dg.y, v_dg.z, v_dg.w};
        const uint8_t ma[4] = {v_m.x, v_m.y, v_m.z, v_m.w};
#pragma unroll
        for (int e = 0; e < 4; ++e) {
            const float dgv = dga[e], dpv = dpa[e];
            const bool vm = ma[e] && finitef(dgv) && (dgv > 1e-6f);
            const bool m2 = vm && finitef(dpv) && (dpv > EPSF);
            const float ratio = dpv / fmaxf(dgv, EPSF);
            const bool fm = m2 && finitef(ratio);
            const uint32_t key = fm ? __float_as_uint(ratio) : SENT;
            if ((key >> 21) == pm)
                atomicAdd(&lh[(key >> 13) & 255u], 1u);
        }
    }
    __syncthreads();

    uint32_t* pout = ws + OFF_PHB + (size_t)(img * HBLK + blk) * 256;
    if (t < 256) pout[t] = lh[t];
}

// ======= main loss: hist0-shaped (512 thr, 16 blk/img, 6-iter loop) + select prologue =======
// Select replicated per block from 256-bin partials (16 KB L2/block; all blocks
// agree). 19-bit prefix + midpoint median: rel err <= 4.9e-4 -> loss err ~3e-3
// << 7.6e-2 threshold (r14-validated: absmax 0.0). Pose in blk 0.
__global__ __launch_bounds__(HTHR) void main_loss(
    const float* __restrict__ dp, const float* __restrict__ dg,
    const uint8_t* __restrict__ vmask, const float* __restrict__ pts_pred,
    const float* __restrict__ intr, const float* __restrict__ posegt,
    const float* __restrict__ posepred, uint32_t* __restrict__ ws)
{
    const int img = blockIdx.y, blk = blockIdx.x, t = threadIdx.x;
    __shared__ float sP[17];
    __shared__ uint32_t wsum[4];
    __shared__ int s_bin;

    // ---- select prologue (first 256 threads; 1 bin each) ----
    {
        uint32_t cs = 0, vscan = 0;
        if (t < 256) {
            const uint32_t* ph = ws + OFF_PHB + (size_t)img * HBLK * 256;
            for (int b = 0; b < HBLK; ++b) cs += ph[b * 256 + t];
            uint32_t v = cs;
#pragma unroll
            for (int o = 1; o < 64; o <<= 1) {
                const uint32_t u = __shfl_up(v, o);
                if ((t & 63) >= o) v += u;
            }
            vscan = v;
            if ((t & 63) == 63) wsum[t >> 6] = v;
        }
        if (t == 0) s_bin = 0;
        __syncthreads();
        if (t < 256) {
            uint32_t woff = 0;
            for (int w = 0; w < (t >> 6); ++w) woff += wsum[w];
            const uint32_t incl = woff + vscan;
            const uint32_t excl = incl - cs;
            const uint32_t k = (uint32_t)((const int*)(ws + OFF_KREM1))[img];
            if (k >= excl && k < incl) s_bin = t;
        }
        __syncthreads();
    }
    if (t == 0) {
        const uint32_t med_u = (ws + OFF_PREF1)[img] | ((uint32_t)s_bin << 13) | 4096u;
        float sc_ = fminf(fmaxf(__uint_as_float(med_u), 0.001f), 1000.0f);
        const int fcnt = ((const int*)(ws + OFF_FCNT))[img];
        const int msum = ((const int*)(ws + OFF_MSUM))[img];
        if (msum < 16 || fcnt == 0) sc_ = 1.0f;

        const float* p = posegt + img * 16;
        sP[0] = p[0]; sP[1] = p[1]; sP[2] = p[2];  sP[9]  = p[3];
        sP[3] = p[4]; sP[4] = p[5]; sP[5] = p[6];  sP[10] = p[7];
        sP[6] = p[8]; sP[7] = p[9]; sP[8] = p[10]; sP[11] = p[11];
        sP[12] = intr[img * 9 + 0]; sP[13] = intr[img * 9 + 4];
        sP[14] = intr[img * 9 + 2]; sP[15] = intr[img * 9 + 5];
        sP[16] = sc_;

        if (blk == 0) {
            // ---- pose encoding + smooth L1 (one thread per image) ----
            const float m00 = p[0], m01 = p[1], m02 = p[2], tx = p[3];
            const float m10 = p[4], m11 = p[5], m12 = p[6], ty = p[7];
            const float m20 = p[8], m21 = p[9], m22 = p[10], tz = p[11];
            float qa[4];
            qa[0] = sqrtf(fmaxf(1.0f + m00 + m11 + m22, 0.0f));
            qa[1] = sqrtf(fmaxf(1.0f + m00 - m11 - m22, 0.0f));
            qa[2] = sqrtf(fmaxf(1.0f - m00 + m11 - m22, 0.0f));
            qa[3] = sqrtf(fmaxf(1.0f - m00 - m11 + m22, 0.0f));
            int best = 0; float bv = qa[0];
            for (int i2 = 1; i2 < 4; ++i2) if (qa[i2] > bv) { bv = qa[i2]; best = i2; }
            float c0, c1, c2, c3;
            if (best == 0)      { c0 = qa[0]*qa[0]; c1 = m21 - m12;   c2 = m02 - m20;   c3 = m10 - m01; }
            else if (best == 1) { c0 = m21 - m12;   c1 = qa[1]*qa[1]; c2 = m10 + m01;   c3 = m02 + m20; }
            else if (best == 2) { c0 = m02 - m20;   c1 = m10 + m01;   c2 = qa[2]*qa[2]; c3 = m12 + m21; }
            else                { c0 = m10 - m01;   c1 = m20 + m02;   c2 = m21 + m12;   c3 = qa[3]*qa[3]; }
            const float denom = 2.0f * fmaxf(qa[best], 0.1f);
            float q0 = c0 / denom, q1 = c1 / denom, q2 = c2 / denom, q3 = c3 / denom;
            if (q0 < 0.0f) { q0 = -q0; q1 = -q1; q2 = -q2; q3 = -q3; }
            const float fovh = 2.0f * atanf((H_ * 0.5f) / sP[13]);
            const float fovw = 2.0f * atanf((W_ * 0.5f) / sP[12]);
            const float pg[9] = {tx * sc_, ty * sc_, tz * sc_, q0, q1, q2, q3, fovh, fovw};
            const float* ppred = posepred + img * 9;
            float s = 0.0f;
            for (int i2 = 0; i2 < 9; ++i2) {
                const float d = fabsf(ppred[i2] - pg[i2]);
                s += (d < 1.0f) ? 0.5f * d * d : d - 0.5f;
            }
            ((float*)(ws + OFF_POSE))[img] = s;
        }
    }
    __syncthreads();
    const float R00 = sP[0], R01 = sP[1], R02 = sP[2];
    const float R10 = sP[3], R11 = sP[4], R12 = sP[5];
    const float R20 = sP[6], R21 = sP[7], R22 = sP[8];
    const float T0 = sP[9], T1 = sP[10], T2 = sP[11];
    const float inv_fx = 1.0f / fmaxf(sP[12], EPSF);
    const float inv_fy = 1.0f / fmaxf(sP[13], EPSF);
    const float cx = sP[14], cy = sP[15];
    const float sc = sP[16];

    const size_t base = (size_t)img * HW_;
    const float* dpi = dp + base;
    const float* dgi = dg + base;

    float dsum = 0.0f, psum = 0.0f, nsum = 0.0f;
    float vcnt = 0.0f, ncnt = 0.0f;

    for (int c = 0; c < CITER; ++c) {
        const int pix = blk * PXB + c * (HTHR * 4) + t * 4;
        const int i = pix >> 9;
        const int j0 = pix & 511;

        const float4 v_dp = *reinterpret_cast<const float4*>(dpi + pix);
        const float4 v_dg = *reinterpret_cast<const float4*>(dgi + pix);
        const uchar4 v_m  = *reinterpret_cast<const uchar4*>(vmask + base + pix);
        const float4 pp0 = *reinterpret_cast<const float4*>(pts_pred + (base + pix) * 3);
        const float4 pp1 = *reinterpret_cast<const float4*>(pts_pred + (base + pix) * 3 + 4);
        const float4 pp2 = *reinterpret_cast<const float4*>(pts_pred + (base + pix) * 3 + 8);

        const int im = (i > 0) ? i - 1 : 0;
        const int ip = (i < H_ - 1) ? i + 1 : i;
        const int jme = (j0 > 0) ? j0 - 1 : 0;
        const int jpe = (j0 + 4 < W_) ? j0 + 4 : W_ - 1;
        const float4 dpU = *reinterpret_cast<const float4*>(dpi + im * W_ + j0);
        const float4 dpD = *reinterpret_cast<const float4*>(dpi + ip * W_ + j0);
        const float4 dgU = *reinterpret_cast<const float4*>(dgi + im * W_ + j0);
        const float4 dgD = *reinterpret_cast<const float4*>(dgi + ip * W_ + j0);
        const float dpLe = dpi[i * W_ + jme], dpRe = dpi[i * W_ + jpe];
        const float dgLe = dgi[i * W_ + jme], dgRe = dgi[i * W_ + jpe];

        const float ppv[12] = {pp0.x, pp0.y, pp0.z, pp0.w, pp1.x, pp1.y, pp1.z, pp1.w,
                               pp2.x, pp2.y, pp2.z, pp2.w};
        const float dpa[4] = {v_dp.x, v_dp.y, v_dp.z, v_dp.w};
        const float dga[4] = {v_dg.x, v_dg.y, v_dg.z, v_dg.w};
        const float dpUa[4] = {dpU.x, dpU.y, dpU.z, dpU.w};
        const float dpDa[4] = {dpD.x, dpD.y, dpD.z, dpD.w};
        const float dgUa[4] = {dgU.x, dgU.y, dgU.z, dgU.w};
        const float dgDa[4] = {dgD.x, dgD.y, dgD.z, dgD.w};
        const uint8_t ma[4] = {v_m.x, v_m.y, v_m.z, v_m.w};

        const float ay = ((float)i - cy) * inv_fy;
        const bool row_int = (i >= 1) && (i <= H_ - 2);

#pragma unroll
        for (int e = 0; e < 4; ++e) {
            const int j = j0 + e;
            const float dgv = dga[e], dpv = dpa[e];
            const bool vm = ma[e] && finitef(dgv) && (dgv > 1e-6f);
            const bool nm = vm && row_int && (j >= 1) && (j <= W_ - 2);
            vcnt += vm ? 1.0f : 0.0f;
            ncnt += nm ? 1.0f : 0.0f;

            const float dal = dgv * sc;
            dsum += vm ? fabsf(dpv - dal) : 0.0f;
            const float ax = ((float)j - cx) * inv_fx;
            const float cxx = ax * dal, cyy = ay * dal;
            const float wx = R00 * cxx + R01 * cyy + R02 * dal + T0;
            const float wy = R10 * cxx + R11 * cyy + R12 * dal + T1;
            const float wz = R20 * cxx + R21 * cyy + R22 * dal + T2;
            const float pl = fabsf(ppv[3 * e] - wx) + fabsf(ppv[3 * e + 1] - wy)
                           + fabsf(ppv[3 * e + 2] - wz);
            psum += vm ? pl : 0.0f;

            const float pdL = (e == 0) ? dpLe : dpa[e - 1];
            const float pdR = (e == 3) ? dpRe : dpa[e + 1];
            const float gdL = (e == 0) ? dgLe : dga[e - 1];
            const float gdR = (e == 3) ? dgRe : dga[e + 1];
            const float pdU = dpUa[e], pdD = dpDa[e];
            const float gdU = dgUa[e], gdD = dgDa[e];

            // simplified cross algebra (r12-verified)
            const float dRLp = pdR - pdL, dDUp = pdD - pdU;
            const float Ap = inv_fy * (pdD + pdU);
            const float Bp = inv_fx * (pdR + pdL);
            const float cpx = dRLp * Ap;
            const float cpy = dDUp * Bp;
            const float cpz = -(Ap * Bp + ax * cpx + ay * cpy);
            const float dRLg = gdR - gdL, dDUg = gdD - gdU;
            const float Ag = inv_fy * (gdD + gdU);
            const float Bg = inv_fx * (gdR + gdL);
            const float cgx = dRLg * Ag;
            const float cgy = dDUg * Bg;
            const float cgz = -(Ag * Bg + ax * cgx + ay * cgy);

            const float np2 = cpx * cpx + cpy * cpy + cpz * cpz;
            const float ng2 = cgx * cgx + cgy * cgy + cgz * cgz;
            const float dpg = cpx * cgx + cpy * cgy + cpz * cgz;
            const float den = fmaxf(np2, 1e-12f) * fmaxf(ng2, 1e-12f);
            float cosv = dpg * __builtin_amdgcn_rsqf(den);
            cosv = fminf(fmaxf(cosv, -1.0f), 1.0f);
            nsum += nm ? (1.0f - cosv) : 0.0f;
        }
    }

    float vals[5] = {vcnt, dsum, psum, nsum, ncnt};
    __shared__ float red[8][5];
    const int wave = t >> 6, lane = t & 63;
#pragma unroll
    for (int q = 0; q < 5; ++q) {
        float v = vals[q];
        for (int o = 32; o > 0; o >>= 1) v += __shfl_down(v, o);
        if (lane == 0) red[wave][q] = v;
    }
    __syncthreads();
    if (t == 0) {
        const int slot = img * HBLK + blk;
        float* part = (float*)(ws + OFF_PART) + slot * 5;
#pragma unroll
        for (int q = 0; q < 5; ++q) {
            float s = 0.0f;
            for (int w = 0; w < 8; ++w) s += red[w][q];
            part[q] = s;
        }
    }
}

// ======= finalize =======
__global__ __launch_bounds__(256) void finalize_k(const uint32_t* __restrict__ ws,
                                                  float* __restrict__ out)
{
    const float* part = (const float*)(ws + OFF_PART);
    const int t = threadIdx.x;
    double s[5] = {0, 0, 0, 0, 0};
    for (int slot = t; slot < NPARTS; slot += 256) {
#pragma unroll
        for (int q = 0; q < 5; ++q) s[q] += (double)part[slot * 5 + q];
    }
    __shared__ double red[4][5];
    const int wave = t >> 6, lane = t & 63;
#pragma unroll
    for (int q = 0; q < 5; ++q) {
        double v = s[q];
        for (int o = 32; o > 0; o >>= 1) v += __shfl_down(v, o);
        if (lane == 0) red[wave][q] = v;
    }
    __syncthreads();
    if (t == 0) {
        double tot[5];
#pragma unroll
        for (int q = 0; q < 5; ++q)
            tot[q] = red[0][q] + red[1][q] + red[2][q] + red[3][q];
        const float* pose = (const float*)(ws + OFF_POSE);
        double ps = 0.0;
        for (int i2 = 0; i2 < NIMG; ++i2) ps += (double)pose[i2];
        const double vmc = tot[0];
        const double depth_loss  = tot[1] / fmax(vmc, 1.0);
        const double points_loss = tot[2] / fmax(3.0 * vmc, 1.0);
        const double normal_loss = tot[3] / fmax(tot[4], 1.0);
        const double pose_loss   = ps / 288.0;
        out[0] = (float)(pose_loss + depth_loss + points_loss + 0.1 * normal_loss);
    }
}

extern "C" void kernel_launch(void* const* d_in, const int* in_sizes, int n_in,
                              void* d_out, int out_size, void* d_ws, size_t ws_size,
                              hipStream_t stream)
{
    const float*   dp       = (const float*)d_in[0];
    const float*   pts_pred = (const float*)d_in[1];
    const float*   posepred = (const float*)d_in[2];
    const float*   dg       = (const float*)d_in[3];
    const float*   intr     = (const float*)d_in[4];
    const float*   posegt   = (const float*)d_in[5];
    const uint8_t* vmask    = (const uint8_t*)d_in[6];
    float* out = (float*)d_out;
    uint32_t* ws = (uint32_t*)d_ws;

    const dim3 hgrid(HBLK, NIMG);
    hist0_k<<<hgrid, HTHR, 0, stream>>>(dp, dg, vmask, ws);
    histp1_k<<<hgrid, HTHR, 0, stream>>>(dp, dg, vmask, ws);
    main_loss<<<hgrid, HTHR, 0, stream>>>(dp, dg, vmask, pts_pred, intr, posegt, posepred, ws);
    finalize_k<<<1, 256, 0, stream>>>(ws, out);
}